// Round 2
// baseline (1177.340 us; speedup 1.0000x reference)
//
#include <hip/hip_runtime.h>
#include <hip/hip_bf16.h>
#include <stdint.h>

typedef _Float16 f16x8 __attribute__((ext_vector_type(8)));
typedef float f32x4 __attribute__((ext_vector_type(4)));
typedef unsigned long long u64;
typedef unsigned int u32;

#define N_CODES 16384
#define N_VEC   16384

#define OUT_LOSS_OFF 4194304
#define OUT_IDX_OFF  4194305

// ws layout (bytes)
#define WS_EHI   0u
#define WS_ELO   8388608u
#define WS_E2    16777216u
#define WS_PART  16842752u   // u64 [4 splits][16384 rows] = 524288 B
#define WS_FKEY  17367040u   // u64 [16384] = 131072 B
#define WS_COUNT 17498112u   // 16 B
#define WS_LIST  17498128u   // 512 ints = 2048 B
#define WS_FBIT  17500176u   // 16384 u32 = 65536 B

#define MARGIN 4.0e-3f
#define CAP 512

#define A_STRIDE 264                      // 256 + 8 pad (f16 units)
#define LDS_BYTES (128 * A_STRIDE * 2)    // 67584 -> 2 blocks/CU

__device__ __forceinline__ u32 sortable_from_f32(float f) {
  u32 u = __float_as_uint(f);
  return (u & 0x80000000u) ? ~u : (u | 0x80000000u);
}
__device__ __forceinline__ float f32_from_sortable(u32 s) {
  u32 u = (s & 0x80000000u) ? (s & 0x7FFFFFFFu) : ~s;
  return __uint_as_float(u);
}

__device__ __forceinline__ void flag_row(int row, int* count, int* list, u32* fbit) {
  if (atomicExch(&fbit[row], 1u) == 0u) {
    const int p = atomicAdd(count, 1);
    if (p < CAP) list[p] = row;
  }
}

// ---------------- prep: embedding -> f16 hi/lo + exact ||e||^2 ----------------
__global__ __launch_bounds__(256) void k_prep(const float* __restrict__ emb,
                                              _Float16* __restrict__ ehi,
                                              _Float16* __restrict__ elo,
                                              float* __restrict__ e2) {
  const int code = blockIdx.x * 4 + (threadIdx.x >> 6);
  const int lane = threadIdx.x & 63;
  const float4 v = ((const float4*)emb)[code * 64 + lane];
  union { _Float16 f[4]; uint2 u2; } ph, pl;
  float vv[4] = {v.x, v.y, v.z, v.w};
  double s = 0.0;
#pragma unroll
  for (int j = 0; j < 4; ++j) {
    _Float16 h = (_Float16)vv[j];
    _Float16 l = (_Float16)(vv[j] - (float)h);
    ph.f[j] = h; pl.f[j] = l;
    s += (double)vv[j] * (double)vv[j];
  }
  ((uint2*)ehi)[code * 64 + lane] = ph.u2;
  ((uint2*)elo)[code * 64 + lane] = pl.u2;
#pragma unroll
  for (int off = 32; off; off >>= 1) s += __shfl_down(s, off);
  if (lane == 0) e2[code] = (float)s;
}

// ---------------- main fused GEMM + per-split argmin/top2 ----------------
// grid 512: blockIdx & 127 = row tile (128 rows), blockIdx >> 7 = code split (4096 codes)
// Per wave: 32 rows (A-hi in regs, A-lo resident in LDS), sweeps all split codes,
// B fragments loaded direct global->VGPR (double-buffered). No in-loop barriers.
__global__ __launch_bounds__(256, 2) void k_gemm(const float* __restrict__ z,
                                                 const _Float16* __restrict__ ehi,
                                                 const _Float16* __restrict__ elo,
                                                 const float* __restrict__ e2,
                                                 u64* __restrict__ part,
                                                 int* __restrict__ count,
                                                 int* __restrict__ list,
                                                 u32* __restrict__ fbit) {
  extern __shared__ char smem_raw[];
  _Float16* Asm = (_Float16*)smem_raw;

  const int tid = threadIdx.x;
  const int rt = blockIdx.x & 127;
  const int split = blockIdx.x >> 7;
  const int row0 = rt * 128;
  const int bb = row0 >> 10, hw0 = row0 & 1023;

  const float4* z4 = (const float4*)z;

  // ---- phase 1: stage A-hi tile (128 rows x 256 dims), NCHW transpose ----
  {
    const int fq = tid & 31, cg = tid >> 5;
    for (int i = 0; i < 32; ++i) {
      const int c = i * 8 + cg;
      float4 v = z4[(bb * 256 + c) * 256 + (hw0 >> 2) + fq];
      float vv[4] = {v.x, v.y, v.z, v.w};
      const int r = fq * 4;
#pragma unroll
      for (int j = 0; j < 4; ++j)
        Asm[(r + j) * A_STRIDE + c] = (_Float16)vv[j];
    }
  }
  __syncthreads();

  const int lane = tid & 63, w = tid >> 6;
  const int fr = lane & 15, q = lane >> 4;
  const int rbase = w * 32;

  // A-hi fragments -> registers (2 row-frags x 8 k-steps)
  f16x8 ah[2][8];
#pragma unroll
  for (int mf = 0; mf < 2; ++mf)
#pragma unroll
    for (int kc = 0; kc < 8; ++kc)
      ah[mf][kc] = *(const f16x8*)&Asm[(rbase + mf * 16 + fr) * A_STRIDE + kc * 32 + q * 8];
  __syncthreads();

  // ---- phase 2: stage A-lo into same LDS (stays resident for the sweep) ----
  {
    const int fq = tid & 31, cg = tid >> 5;
    for (int i = 0; i < 32; ++i) {
      const int c = i * 8 + cg;
      float4 v = z4[(bb * 256 + c) * 256 + (hw0 >> 2) + fq];
      float vv[4] = {v.x, v.y, v.z, v.w};
      const int r = fq * 4;
#pragma unroll
      for (int j = 0; j < 4; ++j) {
        float f = vv[j];
        _Float16 h = (_Float16)f;
        Asm[(r + j) * A_STRIDE + c] = (_Float16)(f - (float)h);
      }
    }
  }
  __syncthreads();

  // ---- code sweep: 128 tiles of 32 codes, K=256 in 8 steps of 32 ----
  const int cb0 = split * 4096;
  u32 o0 = (u32)(cb0 + fr) * 512u + (u32)q * 16u;  // byte offset for nf=0 frag
  u32 o1 = o0 + 8192u;                              // nf=1 (+16 codes * 512 B)

  const char* EH = (const char*)ehi;
  const char* EL = (const char*)elo;

#define LDB(base, off, kcc) (*(const f16x8*)((base) + (off) + (kcc) * 64))

  f16x8 bh[2][2], bl[2][2];
  bh[0][0] = LDB(EH, o0, 0); bh[0][1] = LDB(EH, o1, 0);
  bl[0][0] = LDB(EL, o0, 0); bl[0][1] = LDB(EL, o1, 0);

  f32x4 acc[2][2] = {};
  u64 k1[2][4], k2[2][4];
#pragma unroll
  for (int mf = 0; mf < 2; ++mf)
#pragma unroll
    for (int rg = 0; rg < 4; ++rg) { k1[mf][rg] = ~0ull; k2[mf][rg] = ~0ull; }

  const u32 lds_a0 = (u32)(rbase + fr) * A_STRIDE;
  const u32 lds_a1 = (u32)(rbase + 16 + fr) * A_STRIDE;

  for (int t = 0; t < 128; ++t) {
#pragma unroll
    for (int kc = 0; kc < 8; ++kc) {
      const int cur = kc & 1, nxt = cur ^ 1;
      if (kc == 7) { o0 += 16384u; o1 += 16384u; }   // advance to next 32-code tile
      const int kn = (kc + 1) & 7;
      // prefetch next k-step (tail overrun reads stay inside ws -> harmless)
      bh[nxt][0] = LDB(EH, o0, kn); bh[nxt][1] = LDB(EH, o1, kn);
      bl[nxt][0] = LDB(EL, o0, kn); bl[nxt][1] = LDB(EL, o1, kn);

      const f16x8 al0 = *(const f16x8*)&Asm[lds_a0 + kc * 32 + q * 8];
      const f16x8 al1 = *(const f16x8*)&Asm[lds_a1 + kc * 32 + q * 8];

#pragma unroll
      for (int nf = 0; nf < 2; ++nf) {
        acc[0][nf] = __builtin_amdgcn_mfma_f32_16x16x32_f16(ah[0][kc], bh[cur][nf], acc[0][nf], 0, 0, 0);
        acc[0][nf] = __builtin_amdgcn_mfma_f32_16x16x32_f16(al0,       bh[cur][nf], acc[0][nf], 0, 0, 0);
        acc[0][nf] = __builtin_amdgcn_mfma_f32_16x16x32_f16(ah[0][kc], bl[cur][nf], acc[0][nf], 0, 0, 0);
        acc[1][nf] = __builtin_amdgcn_mfma_f32_16x16x32_f16(ah[1][kc], bh[cur][nf], acc[1][nf], 0, 0, 0);
        acc[1][nf] = __builtin_amdgcn_mfma_f32_16x16x32_f16(al1,       bh[cur][nf], acc[1][nf], 0, 0, 0);
        acc[1][nf] = __builtin_amdgcn_mfma_f32_16x16x32_f16(ah[1][kc], bl[cur][nf], acc[1][nf], 0, 0, 0);
      }
    }

    // epilogue: score = ||e||^2 - 2*dot ; per-lane top-2 keys
    const int cb = cb0 + t * 32;
#pragma unroll
    for (int nf = 0; nf < 2; ++nf) {
      const int gcode = cb + nf * 16 + fr;
      const float ev = e2[gcode];
#pragma unroll
      for (int mf = 0; mf < 2; ++mf) {
#pragma unroll
        for (int rg = 0; rg < 4; ++rg) {
          const float sc = ev - 2.0f * acc[mf][nf][rg];
          const u64 key = ((u64)sortable_from_f32(sc) << 32) | (u32)gcode;
          const u64 old1 = k1[mf][rg];
          const bool lt = key < old1;
          k1[mf][rg] = lt ? key : old1;
          const u64 cand2 = lt ? old1 : key;
          const u64 old2 = k2[mf][rg];
          k2[mf][rg] = cand2 < old2 ? cand2 : old2;
        }
      }
    }
#pragma unroll
    for (int mf = 0; mf < 2; ++mf)
#pragma unroll
      for (int nf = 0; nf < 2; ++nf) acc[mf][nf] = (f32x4){0.0f, 0.0f, 0.0f, 0.0f};
  }

  // ---- reduce top-2 across the 16 column-lanes; write per-split min + local flag ----
#pragma unroll
  for (int mf = 0; mf < 2; ++mf) {
#pragma unroll
    for (int rg = 0; rg < 4; ++rg) {
      u64 a1 = k1[mf][rg], a2 = k2[mf][rg];
#pragma unroll
      for (int off = 1; off < 16; off <<= 1) {
        u64 b1 = __shfl_xor(a1, off);
        u64 b2 = __shfl_xor(a2, off);
        u64 n1 = a1 < b1 ? a1 : b1;
        u64 mx = a1 < b1 ? b1 : a1;
        u64 mn2 = a2 < b2 ? a2 : b2;
        a1 = n1;
        a2 = mx < mn2 ? mx : mn2;
      }
      if (fr == 0) {
        const int row = row0 + rbase + mf * 16 + q * 4 + rg;
        part[split * N_VEC + row] = a1;
        const float s1 = f32_from_sortable((u32)(a1 >> 32));
        const float s2 = f32_from_sortable((u32)(a2 >> 32));
        if (s2 - s1 < MARGIN) flag_row(row, count, list, fbit);
      }
    }
  }
}

// ---------------- merge splits, flag cross-split near-ties ----------------
__global__ __launch_bounds__(256) void k_merge(const u64* __restrict__ part,
                                               u64* __restrict__ fkey,
                                               int* __restrict__ count,
                                               int* __restrict__ list,
                                               u32* __restrict__ fbit) {
  const int r = blockIdx.x * 256 + threadIdx.x;
  const u64 v0 = part[r];
  const u64 v1 = part[N_VEC + r];
  const u64 v2 = part[2 * N_VEC + r];
  const u64 v3 = part[3 * N_VEC + r];
  const u64 lo01 = v0 < v1 ? v0 : v1, hi01 = v0 < v1 ? v1 : v0;
  const u64 lo23 = v2 < v3 ? v2 : v3, hi23 = v2 < v3 ? v3 : v2;
  const u64 m1 = lo01 < lo23 ? lo01 : lo23;
  const u64 mxlo = lo01 < lo23 ? lo23 : lo01;
  const u64 mnhi = hi01 < hi23 ? hi01 : hi23;
  const u64 m2 = mxlo < mnhi ? mxlo : mnhi;
  const float s1 = f32_from_sortable((u32)(m1 >> 32));
  const float s2 = f32_from_sortable((u32)(m2 >> 32));
  if ((s2 - s1 < MARGIN) || (fbit[r] != 0u)) {
    fkey[r] = ~0ull;
    flag_row(r, count, list, fbit);
  } else {
    fkey[r] = m1;
  }
}

// ---------------- exact fp64 rescue for flagged rows ----------------
// grid 16384: blockIdx>>5 = list slot (512), blockIdx&31 = code chunk (512 codes)
__global__ __launch_bounds__(256) void k_rescue(const float* __restrict__ z,
                                                const float* __restrict__ emb,
                                                const int* __restrict__ count,
                                                const int* __restrict__ list,
                                                u64* __restrict__ fkey) {
  const int li = blockIdx.x >> 5;
  const int chunk = blockIdx.x & 31;
  int cnt = *count; if (cnt > CAP) cnt = CAP;
  if (li >= cnt) return;
  const int row = list[li];
  __shared__ float zl[256];
  const int b = row >> 10, hw = row & 1023;
  zl[threadIdx.x] = z[(b * 256 + threadIdx.x) * 1024 + hw];
  __syncthreads();
  const int lane = threadIdx.x & 63, wvi = threadIdx.x >> 6;
  const int c0 = lane * 4;
  const float z0 = zl[c0], z1 = zl[c0 + 1], z2 = zl[c0 + 2], z3 = zl[c0 + 3];
  u64 local = ~0ull;
  for (int it = 0; it < 128; ++it) {
    const int code = chunk * 512 + wvi * 128 + it;
    const float4 e4 = ((const float4*)emb)[code * 64 + lane];
    double dz = (double)e4.x * z0 + (double)e4.y * z1 + (double)e4.z * z2 + (double)e4.w * z3;
    double de = (double)e4.x * e4.x + (double)e4.y * e4.y + (double)e4.z * e4.z + (double)e4.w * e4.w;
#pragma unroll
    for (int off = 32; off; off >>= 1) { dz += __shfl_down(dz, off); de += __shfl_down(de, off); }
    if (lane == 0) {
      const double sc = de - 2.0 * dz;
      long long qv = (long long)((sc + 1024.0) * 8589934592.0);   // 2^33 fixed point
      if (qv < 0) qv = 0;
      const u64 key = ((u64)qv << 14) | (u32)code;
      if (key < local) local = key;
    }
  }
  if (lane == 0) atomicMin(fkey + row, local);
}

// ---------------- output: z_q (straight-through), loss, indices ----------------
__global__ __launch_bounds__(256) void k_out(const float* __restrict__ z,
                                             const float* __restrict__ emb,
                                             const u64* __restrict__ fkey,
                                             float* __restrict__ out) {
  const int gid = blockIdx.x * 256 + threadIdx.x;   // float4 units
  const int f0 = gid * 4;
  const int bc = f0 >> 10;
  const int hw = f0 & 1023;
  const int c = bc & 255, b = bc >> 8;
  const int n = b * 1024 + hw;
  const float4 z4 = ((const float4*)z)[gid];
  float zz[4] = {z4.x, z4.y, z4.z, z4.w};
  float o[4];
#pragma unroll
  for (int j = 0; j < 4; ++j) {
    const int idx = (int)(fkey[n + j] & 0x3FFFull);
    const float ev = emb[idx * 256 + c];
    o[j] = zz[j] + (ev - zz[j]);
  }
  float4 ov = {o[0], o[1], o[2], o[3]};
  ((float4*)out)[gid] = ov;
  if (gid == 0) out[OUT_LOSS_OFF] = 0.0f;
  if (gid < N_VEC) out[OUT_IDX_OFF + gid] = (float)(u32)(fkey[gid] & 0x3FFFull);
}

extern "C" void kernel_launch(void* const* d_in, const int* in_sizes, int n_in,
                              void* d_out, int out_size, void* d_ws, size_t ws_size,
                              hipStream_t stream) {
  const float* z = (const float*)d_in[0];
  const float* emb = (const float*)d_in[1];
  float* out = (float*)d_out;
  char* ws = (char*)d_ws;

  _Float16* ehi = (_Float16*)(ws + WS_EHI);
  _Float16* elo = (_Float16*)(ws + WS_ELO);
  float* e2 = (float*)(ws + WS_E2);
  u64* part = (u64*)(ws + WS_PART);
  u64* fkey = (u64*)(ws + WS_FKEY);
  int* count = (int*)(ws + WS_COUNT);
  int* list = (int*)(ws + WS_LIST);
  u32* fbit = (u32*)(ws + WS_FBIT);

  hipFuncSetAttribute((const void*)k_gemm, hipFuncAttributeMaxDynamicSharedMemorySize,
                      LDS_BYTES);
  hipMemsetAsync(ws + WS_COUNT, 0, 16, stream);
  hipMemsetAsync(ws + WS_FBIT, 0, 65536, stream);

  k_prep<<<4096, 256, 0, stream>>>(emb, ehi, elo, e2);
  k_gemm<<<512, 256, LDS_BYTES, stream>>>(z, ehi, elo, e2, part, count, list, fbit);
  k_merge<<<64, 256, 0, stream>>>(part, fkey, count, list, fbit);
  k_rescue<<<16384, 256, 0, stream>>>(z, emb, count, list, fkey);
  k_out<<<4096, 256, 0, stream>>>(z, emb, fkey, out);
}